// Round 9
// baseline (224.269 us; speedup 1.0000x reference)
//
#include <hip/hip_runtime.h>
#include <hip/hip_bf16.h>
#include <math.h>

// out = tanh(x * sigmoid(x)) + sigmoid(x), elementwise fp32, N = 16*2048*4096.
// Memory-bound: 1.073 GB traffic; m13 copy ceiling 6.29 TB/s -> ~171 us floor.
// R8 = 209.8 us (5.12 TB/s). R9: rotated software-pipeline — exact-trip loop,
// prefetch next float4 before computing current, pointer-bump addressing,
// NO unroll (R4-R6 showed unroll-4 regresses, likely VGPR/occupancy step),
// __launch_bounds__(256,8) pins 8 waves/SIMD (VGPR cap 64).

typedef float vfloat4 __attribute__((ext_vector_type(4)));

#define LOG2E 1.44269504088896341f

__device__ __forceinline__ float fast_rcp(float a) {
    return __builtin_amdgcn_rcpf(a);   // v_rcp_f32, ~1 ulp
}

__device__ __forceinline__ float fast_exp(float a) {
    return __builtin_amdgcn_exp2f(a * LOG2E);  // v_exp_f32 computes 2^x
}

__device__ __forceinline__ float act(float v) {
    float s = fast_rcp(1.0f + fast_exp(-v));      // sigmoid(x)
    float z = v * s;                               // silu(x)
    float t = 1.0f - 2.0f * fast_rcp(fast_exp(2.0f * z) + 1.0f);  // tanh(z)
    return t + s;
}

__device__ __forceinline__ vfloat4 act4(vfloat4 v) {
    vfloat4 r;
    r.x = act(v.x);
    r.y = act(v.y);
    r.z = act(v.z);
    r.w = act(v.w);
    return r;
}

__global__ void __launch_bounds__(256, 8)
dynact_kernel(const vfloat4* __restrict__ x4, vfloat4* __restrict__ o4,
              int iters, long long stride) {
    long long i = (long long)blockIdx.x * 256 + threadIdx.x;
    vfloat4 v = x4[i];                       // prologue load
    for (int k = 0; k < iters - 1; ++k) {
        const long long inext = i + stride;
        vfloat4 vn = x4[inext];              // issue next load early
        o4[i] = act4(v);                     // compute+store current (overlaps vn load)
        v = vn;
        i = inext;
    }
    o4[i] = act4(v);                         // epilogue
}

// Remainder float4s beyond iters*stride (guarded).
__global__ void __launch_bounds__(256)
dynact_rem4(const vfloat4* __restrict__ x4, vfloat4* __restrict__ o4,
            long long start, long long n4) {
    long long i = start + (long long)blockIdx.x * blockDim.x + threadIdx.x;
    if (i < n4) {
        o4[i] = act4(x4[i]);
    }
}

// Scalar tail if n % 4 != 0 (not the case here).
__global__ void dynact_tail(const float* __restrict__ x, float* __restrict__ out,
                            long long start, long long n) {
    long long i = start + (long long)blockIdx.x * blockDim.x + threadIdx.x;
    if (i < n) out[i] = act(x[i]);
}

extern "C" void kernel_launch(void* const* d_in, const int* in_sizes, int n_in,
                              void* d_out, int out_size, void* d_ws, size_t ws_size,
                              hipStream_t stream) {
    const float* x = (const float*)d_in[0];
    float* out = (float*)d_out;
    const long long n = (long long)in_sizes[0];
    const long long n4 = n >> 2;

    const int block = 256;
    const int grid = 2048;                       // 8 blocks/CU on 256 CUs
    const long long stride = (long long)grid * block;
    const int iters = (int)(n4 / stride);        // 64 exact for this shape

    if (iters > 0) {
        dynact_kernel<<<grid, block, 0, stream>>>(
            (const vfloat4*)x, (vfloat4*)out, iters, stride);
    }
    const long long done4 = (long long)iters * stride;
    const long long rem4 = n4 - done4;
    if (rem4 > 0) {
        int g = (int)((rem4 + block - 1) / block);
        dynact_rem4<<<g, block, 0, stream>>>((const vfloat4*)x, (vfloat4*)out, done4, n4);
    }
    const long long done = n4 << 2;
    if (n - done > 0) {
        int g = (int)((n - done + block - 1) / block);
        dynact_tail<<<g, block, 0, stream>>>(x, out, done, n);
    }
}

// Round 10
// 178.306 us; speedup vs baseline: 1.2578x; 1.2578x over previous
//
#include <hip/hip_runtime.h>
#include <hip/hip_bf16.h>
#include <math.h>

// out = tanh(x * sigmoid(x)) + sigmoid(x), elementwise fp32, N = 16*2048*4096.
// Memory-bound: 1.073 GB traffic; copy ceiling 6.29 TB/s -> ~171 us floor.
// R10: canonical copy-ubench shape — NO loop, one float4 per thread,
// grid = n4/256 = 131072 blocks. R8 (grid-stride loop, 2048 blocks) = 209.8 us;
// every fancier loop structure regressed. MLP now comes from wave turnover,
// not in-wave loop pipelining.

#define LOG2E 1.44269504088896341f

__device__ __forceinline__ float fast_rcp(float a) {
    return __builtin_amdgcn_rcpf(a);   // v_rcp_f32, ~1 ulp
}

__device__ __forceinline__ float fast_exp(float a) {
    return __builtin_amdgcn_exp2f(a * LOG2E);  // v_exp_f32 computes 2^x
}

__device__ __forceinline__ float act(float v) {
    float s = fast_rcp(1.0f + fast_exp(-v));      // sigmoid(x)
    float z = v * s;                               // silu(x)
    float t = 1.0f - 2.0f * fast_rcp(fast_exp(2.0f * z) + 1.0f);  // tanh(z)
    return t + s;
}

__global__ void __launch_bounds__(256)
dynact_kernel(const float4* __restrict__ x4, float4* __restrict__ o4, long long n4) {
    const long long i = (long long)blockIdx.x * 256 + threadIdx.x;
    if (i < n4) {
        float4 v = x4[i];
        float4 r;
        r.x = act(v.x);
        r.y = act(v.y);
        r.z = act(v.z);
        r.w = act(v.w);
        o4[i] = r;
    }
}

// Scalar tail if n % 4 != 0 (not the case here: 16*2048*4096 % 4 == 0).
__global__ void dynact_tail(const float* __restrict__ x, float* __restrict__ out,
                            long long start, long long n) {
    long long i = start + (long long)blockIdx.x * blockDim.x + threadIdx.x;
    if (i < n) out[i] = act(x[i]);
}

extern "C" void kernel_launch(void* const* d_in, const int* in_sizes, int n_in,
                              void* d_out, int out_size, void* d_ws, size_t ws_size,
                              hipStream_t stream) {
    const float* x = (const float*)d_in[0];
    float* out = (float*)d_out;
    const long long n = (long long)in_sizes[0];
    const long long n4 = n >> 2;

    const int block = 256;
    const long long grid = (n4 + block - 1) / block;   // 131072 for this shape
    if (grid > 0) {
        dynact_kernel<<<(int)grid, block, 0, stream>>>(
            (const float4*)x, (float4*)out, n4);
    }

    const long long done = n4 << 2;
    if (n - done > 0) {
        int g = (int)((n - done + block - 1) / block);
        dynact_tail<<<g, block, 0, stream>>>(x, out, done, n);
    }
}